// Round 13
// baseline (1111.802 us; speedup 1.0000x reference)
//
#include <hip/hip_runtime.h>

// LSTM, B=512 x T=1024, H=100, input_size=1.
// R17 = R16 with the two phases shortened (counters showed zero overlap:
// per-active-CU MfmaUtil 40% + VALUBusy 56% -> 920 + 1290 + serial = 2310
// cyc/step, phase-aligned by the barrier; 14.4 cyc/MFMA = dependency-bound).
//  1. MFMA: 4 chains x 8-deep -> 8 chains x 4-deep (kt01/kt23 split per
//     gate, one f32x4 add to merge): 16 indep chains/SIMD -> issue-bound
//     (~320 cyc, was ~920).
//  2. A-fragments pre-scaled by -log2e (gates i,f,o) / +2*log2e (gate g):
//     sigmoid = rcp(1+exp2(gate)) -- kills the per-gate scale mul; exp2
//     via inline-asm v_exp_f32 (native 2^x).
//  3. tanh folded to fmaf(-2, rcp(1+exp2(.)), 1).
// Everything else identical to R16 (structure comments there).

#define HID   100
#define TLEN  1024
#define NB    16
#define BLOCK 512
#define INSTR 1033   // in_s row stride: 16 lanes at stride-9 banks, no conflict

typedef _Float16 half8 __attribute__((ext_vector_type(8)));
typedef float    f32x4 __attribute__((ext_vector_type(4)));

#define MFMA(A,B,C) __builtin_amdgcn_mfma_f32_16x16x32_f16((A),(B),(C),0,0,0)

#define LOG2E   1.442695041f
#define LOG2E2  2.885390082f

static __device__ __forceinline__ unsigned packh(_Float16 a, _Float16 b) {
    return (unsigned)__builtin_bit_cast(unsigned short, a)
         | ((unsigned)__builtin_bit_cast(unsigned short, b) << 16);
}
static __device__ __forceinline__ float exp2v(float x) {
    float r;
    asm("v_exp_f32 %0, %1" : "=v"(r) : "v"(x));
    return r;
}

__global__ __launch_bounds__(BLOCK, 2)   // 2 waves/EU min -> 256-VGPR budget
void lstm_mfma2(
    const float* __restrict__ input,   // [B, T]
    const float* __restrict__ W_ih,    // [4H]
    const float* __restrict__ W_hh,    // [4H, H]
    const float* __restrict__ b_ih,    // [4H]
    const float* __restrict__ b_hh,    // [4H]
    const float* __restrict__ W_out,   // [H]
    const float* __restrict__ b_out,   // [1]
    float* __restrict__ out)           // [B, T]
{
    const int tid  = threadIdx.x;
    const int lane = tid & 63;
    const int w    = tid >> 6;        // wave 0..7
    const int b0   = blockIdx.x * NB;
    const int q    = lane >> 4;       // k-subgroup / D row-quad
    const int mrow = lane & 15;       // A row within tile / B col n

    // B-fragment LDS: [parity][kt][lane][4 dwords of 2xf16], 8 KB.
    // k = 32*kt + 8*(lane>>4) + elem; same k-formula both operands -> any
    // within-tile k-permutation vs true HW layout cancels in A.B.
    __shared__ __align__(16) unsigned B_lds[2][4][64][4];
    __shared__ float in_s[NB * INSTR];                       // 66 KB

    // ---- one-time staging ----
    for (int i = tid; i < NB * TLEN; i += BLOCK) {
        const int n = i >> 10, t = i & 1023;
        in_s[n * INSTR + t] = input[(b0 + n) * TLEN + t];
    }
    for (int i = tid; i < 2 * 4 * 64 * 4; i += BLOCK)
        ((unsigned*)B_lds)[i] = 0u;

    // ---- A fragments, PRE-SCALED per gate (see header) ----
    half8 Ahi[4][4], Alo[4][4];       // [gate][kt]
    if (w < 7) {
        const int u = 16 * w + mrow;
        #pragma unroll
        for (int g = 0; g < 4; ++g) {
            const float scl = (g == 2) ? LOG2E2 : -LOG2E;
            #pragma unroll
            for (int kt = 0; kt < 4; ++kt) {
                half8 hh, hl;
                #pragma unroll
                for (int j = 0; j < 8; ++j) {
                    const int k = 32 * kt + 8 * q + j;
                    float v = 0.f;
                    if (u < HID) {
                        const int row = HID * g + u;
                        if (k < HID)           v = W_hh[row * HID + k];
                        else if (k == HID)     v = b_ih[row] + b_hh[row];
                        else if (k <= HID + 2) v = W_ih[row];
                    }
                    v *= scl;
                    const _Float16 vh = (_Float16)v;
                    hh[j] = vh;
                    hl[j] = (_Float16)(v - (float)vh);
                }
                Ahi[g][kt] = hh; Alo[g][kt] = hl;
            }
        }
    } else {
        // wave 7: out-row tile, UNSCALED: row 0 = W_out, b_out at k=100.
        #pragma unroll
        for (int kt = 0; kt < 4; ++kt) {
            half8 hh, hl;
            #pragma unroll
            for (int j = 0; j < 8; ++j) {
                const int k = 32 * kt + 8 * q + j;
                float v = 0.f;
                if (mrow == 0) {
                    if (k < HID)       v = W_out[k];
                    else if (k == HID) v = b_out[0];
                }
                const _Float16 vh = (_Float16)v;
                hh[j] = vh;
                hl[j] = (_Float16)(v - (float)vh);
            }
            Ahi[0][kt] = hh; Alo[0][kt] = hl;
            Ahi[1][kt] = hh; Alo[1][kt] = hl;
            Ahi[2][kt] = hh; Alo[2][kt] = hl;
            Ahi[3][kt] = hh; Alo[3][kt] = hl;
        }
    }

    float c0 = 0.f, c1 = 0.f, c2 = 0.f, c3 = 0.f;   // cell state (4/lane)

    __syncthreads();
    // prologue: x[0] + bias-one row into parity 0 (k=100:1, 101:xhi, 102:xlo)
    if (w == 7 && lane < NB) {
        const float xv = in_s[lane * INSTR];
        const _Float16 xh = (_Float16)xv;
        const _Float16 xl = (_Float16)(xv - (float)xh);
        uint2 dv; dv.x = packh((_Float16)1.f, xh); dv.y = packh(xl, (_Float16)0.f);
        *(uint2*)&B_lds[0][3][lane][2] = dv;
    }
    __syncthreads();

    #pragma unroll 1
    for (int t = 0; t < TLEN; ++t) {
        const int p = t & 1;
        const half8 bf0 = *(const half8*)&B_lds[p][0][lane][0];
        const half8 bf1 = *(const half8*)&B_lds[p][1][lane][0];
        const half8 bf2 = *(const half8*)&B_lds[p][2][lane][0];
        const half8 bf3 = *(const half8*)&B_lds[p][3][lane][0];

        if (w < 7) {
            // ---- GEMM: 8 chains x 4-deep (kt01 / kt23 per gate) ----
            f32x4 pA0 = {0.f,0.f,0.f,0.f}, pB0 = {0.f,0.f,0.f,0.f};
            f32x4 pA1 = {0.f,0.f,0.f,0.f}, pB1 = {0.f,0.f,0.f,0.f};
            f32x4 pA2 = {0.f,0.f,0.f,0.f}, pB2 = {0.f,0.f,0.f,0.f};
            f32x4 pA3 = {0.f,0.f,0.f,0.f}, pB3 = {0.f,0.f,0.f,0.f};
            #define QQ(G, PA, PB) \
                PA = MFMA(Ahi[G][0], bf0, PA); PA = MFMA(Alo[G][0], bf0, PA); \
                PA = MFMA(Ahi[G][1], bf1, PA); PA = MFMA(Alo[G][1], bf1, PA); \
                PB = MFMA(Ahi[G][2], bf2, PB); PB = MFMA(Alo[G][2], bf2, PB); \
                PB = MFMA(Ahi[G][3], bf3, PB); PB = MFMA(Alo[G][3], bf3, PB);
            QQ(0, pA0, pB0) QQ(1, pA1, pB1) QQ(2, pA2, pB2) QQ(3, pA3, pB3)
            #undef QQ
            const f32x4 a0 = pA0 + pB0;   // gate i (pre-scaled by -log2e)
            const f32x4 a1 = pA1 + pB1;   // gate f
            const f32x4 a2 = pA2 + pB2;   // gate g (pre-scaled by +2*log2e)
            const f32x4 a3 = pA3 + pB3;   // gate o

            // ---- cell update, in-register (D: col=lane&15, row=4q+r) ----
            _Float16 hh[4];
            #define CELL(R, CR) { \
                const float is = __builtin_amdgcn_rcpf(1.f + exp2v(a0[R])); \
                const float fs = __builtin_amdgcn_rcpf(1.f + exp2v(a1[R])); \
                const float os = __builtin_amdgcn_rcpf(1.f + exp2v(a3[R])); \
                const float gt = fmaf(-2.f, __builtin_amdgcn_rcpf(1.f + exp2v(a2[R])), 1.f); \
                CR = fmaf(fs, CR, is * gt); \
                const float th = fmaf(-2.f, __builtin_amdgcn_rcpf(1.f + exp2v(LOG2E2 * CR)), 1.f); \
                hh[R] = (_Float16)(os * th); }
            CELL(0, c0) CELL(1, c1) CELL(2, c2) CELL(3, c3)
            #undef CELL

            // ---- write h as next-parity B rows (k = U..U+3) ----
            if (w < 6 || q == 0) {
                const int U = 16 * w + 4 * q;
                uint2 dv;
                dv.x = packh(hh[0], hh[1]);
                dv.y = packh(hh[2], hh[3]);
                *(uint2*)&B_lds[p ^ 1][U >> 5][(((U >> 3) & 3) << 4) | mrow]
                               [(U >> 1) & 3] = dv;
            }
        } else {
            // ---- wave 7: out-row tile -> out[t-1]; stage x[t+1] ----
            f32x4 oA = {0.f,0.f,0.f,0.f}, oB = {0.f,0.f,0.f,0.f};
            oA = MFMA(Ahi[0][0], bf0, oA); oA = MFMA(Alo[0][0], bf0, oA);
            oA = MFMA(Ahi[0][1], bf1, oA); oA = MFMA(Alo[0][1], bf1, oA);
            oB = MFMA(Ahi[0][2], bf2, oB); oB = MFMA(Alo[0][2], bf2, oB);
            oB = MFMA(Ahi[0][3], bf3, oB); oB = MFMA(Alo[0][3], bf3, oB);
            const f32x4 ao = oA + oB;
            if (lane < NB) {
                if (t > 0) out[(b0 + lane) * TLEN + (t - 1)] = ao[0];
                if (t + 1 < TLEN) {
                    const float xv = in_s[lane * INSTR + (t + 1)];
                    const _Float16 xh = (_Float16)xv;
                    const _Float16 xl = (_Float16)(xv - (float)xh);
                    uint2 dv; dv.x = packh((_Float16)1.f, xh);
                    dv.y = packh(xl, (_Float16)0.f);
                    *(uint2*)&B_lds[p ^ 1][3][lane][2] = dv;
                }
            }
        }
        __syncthreads();   // the ONLY barrier per step
    }

    // ---- epilogue: out[.,T-1] from h[T-1] (parity 0; bias-one persists) ----
    if (w == 7) {
        const half8 bf0 = *(const half8*)&B_lds[0][0][lane][0];
        const half8 bf1 = *(const half8*)&B_lds[0][1][lane][0];
        const half8 bf2 = *(const half8*)&B_lds[0][2][lane][0];
        const half8 bf3 = *(const half8*)&B_lds[0][3][lane][0];
        f32x4 oA = {0.f,0.f,0.f,0.f}, oB = {0.f,0.f,0.f,0.f};
        oA = MFMA(Ahi[0][0], bf0, oA); oA = MFMA(Alo[0][0], bf0, oA);
        oA = MFMA(Ahi[0][1], bf1, oA); oA = MFMA(Alo[0][1], bf1, oA);
        oB = MFMA(Ahi[0][2], bf2, oB); oB = MFMA(Alo[0][2], bf2, oB);
        oB = MFMA(Ahi[0][3], bf3, oB); oB = MFMA(Alo[0][3], bf3, oB);
        const f32x4 ao = oA + oB;
        if (lane < NB) out[(b0 + lane) * TLEN + (TLEN - 1)] = ao[0];
    }
}

extern "C" void kernel_launch(void* const* d_in, const int* in_sizes, int n_in,
                              void* d_out, int out_size, void* d_ws, size_t ws_size,
                              hipStream_t stream) {
    const float* input = (const float*)d_in[0];
    const float* W_ih  = (const float*)d_in[1];
    const float* W_hh  = (const float*)d_in[2];
    const float* b_ih  = (const float*)d_in[3];
    const float* b_hh  = (const float*)d_in[4];
    const float* W_out = (const float*)d_in[5];
    const float* b_out = (const float*)d_in[6];
    float* out = (float*)d_out;

    const int B = in_sizes[0] / TLEN;  // 512
    lstm_mfma2<<<B / NB, BLOCK, 0, stream>>>(input, W_ih, W_hh, b_ih, b_hh,
                                             W_out, b_out, out);
}

// Round 15
// 816.909 us; speedup vs baseline: 1.3610x; 1.3610x over previous
//
#include <hip/hip_runtime.h>

// LSTM, B=512 x T=1024, H=100, input_size=1.
// R19 = R18 resubmitted verbatim (R18 died to the infra "container failed
// twice" error -- 3rd occurrence; R8->R9 and R15->R16 verbatim resubmits
// both ran fine). Audit: uniform barrier, hi/lo col choreography verified,
// epilogue k=101,102 contribution provably zero, index maps bijective.
//
// R18: R17 showed the step floor is MFMA *CU-throughput*: 4.85 cyc/MFMA is
// per-CU (m06 is a chip-wide ceiling), so R16's 232 MFMA/step = 1125 cyc
// floor + ~500 trans + LDS/barrier = measured 2310-2480. Cut both:
//  1. Single-plane f16 W: 232 -> 116 MFMA/step (floor 563 cyc).
//  2. h hi/lo packed in N: NB=8 batches/block; B cols 0-7 = h_hi, cols
//     8-15 = (h - f16(h))*2^11. gate = D[hi] + 2^-11*D[lo] via shfl_xor 8.
//     Error swaps dominant term h-quant -> W-quant (symmetric ~5e-4).
//  3. Cell halves (3200 cells) + lane-pair redistribution (2 units/lane):
//     trans phase ~halves.
// Skeleton unchanged from R16: 1 barrier/step, gate-aligned tiles, lagged
// out-projection on wave 7, x/bias as extra K rows (zeroed in lo cols).
// 64 blocks x 512 thr.

#define HID   100
#define TLEN  1024
#define NB    8
#define BLOCK 512
#define INSTR 1033   // in_s row stride: conflict-free
#define SC_LO 0.00048828125f   // 2^-11
#define SC_HI 2048.0f          // 2^11

typedef _Float16 half8 __attribute__((ext_vector_type(8)));
typedef float    f32x4 __attribute__((ext_vector_type(4)));

#define MFMA(A,B,C) __builtin_amdgcn_mfma_f32_16x16x32_f16((A),(B),(C),0,0,0)
#define LOG2E   1.442695041f
#define LOG2E2  2.885390082f

static __device__ __forceinline__ unsigned packh(_Float16 a, _Float16 b) {
    return (unsigned)__builtin_bit_cast(unsigned short, a)
         | ((unsigned)__builtin_bit_cast(unsigned short, b) << 16);
}
static __device__ __forceinline__ float exp2v(float x) {
    float r;
    asm("v_exp_f32 %0, %1" : "=v"(r) : "v"(x));
    return r;
}

__global__ __launch_bounds__(BLOCK, 2)   // 2 waves/EU -> 256-reg budget
void lstm_mfma3(
    const float* __restrict__ input,   // [B, T]
    const float* __restrict__ W_ih,    // [4H]
    const float* __restrict__ W_hh,    // [4H, H]
    const float* __restrict__ b_ih,    // [4H]
    const float* __restrict__ b_hh,    // [4H]
    const float* __restrict__ W_out,   // [H]
    const float* __restrict__ b_out,   // [1]
    float* __restrict__ out)           // [B, T]
{
    const int tid  = threadIdx.x;
    const int lane = tid & 63;
    const int w    = tid >> 6;        // wave 0..7
    const int b0   = blockIdx.x * NB;
    const int q    = lane >> 4;       // k-subgroup / D row-quad
    const int mrow = lane & 15;       // A row within tile / B col n
    const int side = (lane >> 3) & 1; // 0: hi col (n<8), 1: lo col (n>=8)

    // B_lds[parity][kt][lane][dword]: k = 32*kt + 8*(lane>>4) + elem.
    // cols 0-7: h_hi (+ bias/x rows); cols 8-15: h_lo*2^11 (bias/x rows 0).
    __shared__ __align__(16) unsigned B_lds[2][4][64][4];
    __shared__ float in_s[NB * INSTR];                     // 33 KB

    for (int i = tid; i < NB * TLEN; i += BLOCK) {
        const int n = i >> 10, t = i & 1023;
        in_s[n * INSTR + t] = input[(b0 + n) * TLEN + t];
    }
    for (int i = tid; i < 2 * 4 * 64 * 4; i += BLOCK)
        ((unsigned*)B_lds)[i] = 0u;

    // ---- A fragments: SINGLE plane f16, gate-scaled (i,f,o: -log2e; g: +2log2e)
    half8 A[4][4];                    // [gate][kt]
    if (w < 7) {
        const int u = 16 * w + mrow;
        #pragma unroll
        for (int g = 0; g < 4; ++g) {
            const float scl = (g == 2) ? LOG2E2 : -LOG2E;
            #pragma unroll
            for (int kt = 0; kt < 4; ++kt) {
                half8 hh;
                #pragma unroll
                for (int j = 0; j < 8; ++j) {
                    const int k = 32 * kt + 8 * q + j;
                    float v = 0.f;
                    if (u < HID) {
                        const int row = HID * g + u;
                        if (k < HID)           v = W_hh[row * HID + k];
                        else if (k == HID)     v = b_ih[row] + b_hh[row];
                        else if (k <= HID + 2) v = W_ih[row];
                    }
                    hh[j] = (_Float16)(v * scl);
                }
                A[g][kt] = hh;
            }
        }
    } else {
        // wave 7: out tile, UNSCALED: row 0 = W_out, b_out at k=100.
        #pragma unroll
        for (int kt = 0; kt < 4; ++kt) {
            half8 hh;
            #pragma unroll
            for (int j = 0; j < 8; ++j) {
                const int k = 32 * kt + 8 * q + j;
                float v = 0.f;
                if (mrow == 0) {
                    if (k < HID)       v = W_out[k];
                    else if (k == HID) v = b_out[0];
                }
                hh[j] = (_Float16)v;
            }
            A[0][kt] = hh; A[1][kt] = hh; A[2][kt] = hh; A[3][kt] = hh;
        }
    }

    float c0 = 0.f, c1 = 0.f;         // cell state: 2 units/lane

    __syncthreads();
    // prologue: x[0]+bias-one into parity 0, HI cols only (k=100..103)
    if (w == 7 && lane < NB) {
        const float xv = in_s[lane * INSTR];
        const _Float16 xh = (_Float16)xv;
        const _Float16 xl = (_Float16)(xv - (float)xh);
        uint2 dv; dv.x = packh((_Float16)1.f, xh); dv.y = packh(xl, (_Float16)0.f);
        *(uint2*)&B_lds[0][3][lane][2] = dv;
    }
    __syncthreads();

    #pragma unroll 1
    for (int t = 0; t < TLEN; ++t) {
        const int p = t & 1;
        const half8 bf0 = *(const half8*)&B_lds[p][0][lane][0];
        const half8 bf1 = *(const half8*)&B_lds[p][1][lane][0];
        const half8 bf2 = *(const half8*)&B_lds[p][2][lane][0];
        const half8 bf3 = *(const half8*)&B_lds[p][3][lane][0];

        if (w < 7) {
            // ---- GEMM: 4 chains x 4-deep = 16 MFMA (single plane) ----
            f32x4 a0 = {0.f,0.f,0.f,0.f}, a1 = {0.f,0.f,0.f,0.f};
            f32x4 a2 = {0.f,0.f,0.f,0.f}, a3 = {0.f,0.f,0.f,0.f};
            a0 = MFMA(A[0][0], bf0, a0); a1 = MFMA(A[1][0], bf0, a1);
            a2 = MFMA(A[2][0], bf0, a2); a3 = MFMA(A[3][0], bf0, a3);
            a0 = MFMA(A[0][1], bf1, a0); a1 = MFMA(A[1][1], bf1, a1);
            a2 = MFMA(A[2][1], bf1, a2); a3 = MFMA(A[3][1], bf1, a3);
            a0 = MFMA(A[0][2], bf2, a0); a1 = MFMA(A[1][2], bf2, a1);
            a2 = MFMA(A[2][2], bf2, a2); a3 = MFMA(A[3][2], bf2, a3);
            a0 = MFMA(A[0][3], bf3, a0); a1 = MFMA(A[1][3], bf3, a1);
            a2 = MFMA(A[2][3], bf3, a2); a3 = MFMA(A[3][3], bf3, a3);

            // ---- exchange: send the rows the PARTNER processes.
            // side0 processes D rows 0,1 (units U+0,U+1), side1 rows 2,3.
            const float si0 = side ? a0[0] : a0[2];
            const float si1 = side ? a0[1] : a0[3];
            const float sf0 = side ? a1[0] : a1[2];
            const float sf1 = side ? a1[1] : a1[3];
            const float sg0 = side ? a2[0] : a2[2];
            const float sg1 = side ? a2[1] : a2[3];
            const float so0 = side ? a3[0] : a3[2];
            const float so1 = side ? a3[1] : a3[3];
            const float ri0 = __shfl_xor(si0, 8);
            const float ri1 = __shfl_xor(si1, 8);
            const float rf0 = __shfl_xor(sf0, 8);
            const float rf1 = __shfl_xor(sf1, 8);
            const float rg0 = __shfl_xor(sg0, 8);
            const float rg1 = __shfl_xor(sg1, 8);
            const float ro0 = __shfl_xor(so0, 8);
            const float ro1 = __shfl_xor(so1, 8);
            const float oi0 = side ? a0[2] : a0[0];
            const float oi1 = side ? a0[3] : a0[1];
            const float of0 = side ? a1[2] : a1[0];
            const float of1 = side ? a1[3] : a1[1];
            const float og0 = side ? a2[2] : a2[0];
            const float og1 = side ? a2[3] : a2[1];
            const float oo0 = side ? a3[2] : a3[0];
            const float oo1 = side ? a3[3] : a3[1];
            // combine hi + 2^-11*lo (side0: own=hi; side1: own=lo)
            const float gi0 = side ? fmaf(SC_LO, oi0, ri0) : fmaf(SC_LO, ri0, oi0);
            const float gi1 = side ? fmaf(SC_LO, oi1, ri1) : fmaf(SC_LO, ri1, oi1);
            const float gf0 = side ? fmaf(SC_LO, of0, rf0) : fmaf(SC_LO, rf0, of0);
            const float gf1 = side ? fmaf(SC_LO, of1, rf1) : fmaf(SC_LO, rf1, of1);
            const float gg0 = side ? fmaf(SC_LO, og0, rg0) : fmaf(SC_LO, rg0, og0);
            const float gg1 = side ? fmaf(SC_LO, og1, rg1) : fmaf(SC_LO, rg1, og1);
            const float go0 = side ? fmaf(SC_LO, oo0, ro0) : fmaf(SC_LO, ro0, oo0);
            const float go1 = side ? fmaf(SC_LO, oo1, ro1) : fmaf(SC_LO, ro1, oo1);

            // ---- cell update: 2 units per lane ----
            float h0f, h1f;
            {
                const float is = __builtin_amdgcn_rcpf(1.f + exp2v(gi0));
                const float fs = __builtin_amdgcn_rcpf(1.f + exp2v(gf0));
                const float os = __builtin_amdgcn_rcpf(1.f + exp2v(go0));
                const float gt = fmaf(-2.f, __builtin_amdgcn_rcpf(1.f + exp2v(gg0)), 1.f);
                c0 = fmaf(fs, c0, is * gt);
                const float th = fmaf(-2.f, __builtin_amdgcn_rcpf(1.f + exp2v(LOG2E2 * c0)), 1.f);
                h0f = os * th;
            }
            {
                const float is = __builtin_amdgcn_rcpf(1.f + exp2v(gi1));
                const float fs = __builtin_amdgcn_rcpf(1.f + exp2v(gf1));
                const float os = __builtin_amdgcn_rcpf(1.f + exp2v(go1));
                const float gt = fmaf(-2.f, __builtin_amdgcn_rcpf(1.f + exp2v(gg1)), 1.f);
                c1 = fmaf(fs, c1, is * gt);
                const float th = fmaf(-2.f, __builtin_amdgcn_rcpf(1.f + exp2v(LOG2E2 * c1)), 1.f);
                h1f = os * th;
            }
            const _Float16 h0h = (_Float16)h0f;
            const _Float16 h1h = (_Float16)h1f;
            const _Float16 h0l = (_Float16)((h0f - (float)h0h) * SC_HI);
            const _Float16 h1l = (_Float16)((h1f - (float)h1h) * SC_HI);
            const unsigned pk_hi = packh(h0h, h1h);
            const unsigned pk_lo = packh(h0l, h1l);
            const unsigned rv_hi = __shfl_xor(pk_hi, 8);
            const unsigned rv_lo = __shfl_xor(pk_lo, 8);
            if (w < 6 || q == 0) {
                const int U = 16 * w + 4 * q;
                uint2 dv;
                dv.x = side ? rv_lo : pk_hi;   // rows U, U+1
                dv.y = side ? pk_lo : rv_hi;   // rows U+2, U+3
                *(uint2*)&B_lds[p ^ 1][U >> 5][(((U >> 3) & 3) << 4) | mrow]
                               [(U >> 1) & 3] = dv;
            }
        } else {
            // ---- wave 7: out tile (4 MFMA) -> out[t-1]; stage x[t+1] ----
            f32x4 ao = {0.f,0.f,0.f,0.f};
            ao = MFMA(A[0][0], bf0, ao);
            ao = MFMA(A[0][1], bf1, ao);
            ao = MFMA(A[0][2], bf2, ao);
            ao = MFMA(A[0][3], bf3, ao);
            const float rv = __shfl_xor(ao[0], 8);   // partner lo col
            if (lane < NB) {
                if (t > 0) out[(b0 + lane) * TLEN + (t - 1)] = fmaf(SC_LO, rv, ao[0]);
                if (t + 1 < TLEN) {
                    const float xv = in_s[lane * INSTR + (t + 1)];
                    const _Float16 xh = (_Float16)xv;
                    const _Float16 xl = (_Float16)(xv - (float)xh);
                    uint2 dv; dv.x = packh((_Float16)1.f, xh);
                    dv.y = packh(xl, (_Float16)0.f);
                    *(uint2*)&B_lds[p ^ 1][3][lane][2] = dv;
                }
            }
        }
        __syncthreads();   // the ONLY barrier per step
    }

    // ---- epilogue: out[.,T-1] from h[T-1] (parity 0; bias-one persists,
    // stale x at k=101,102 multiplies A-zeros) ----
    if (w == 7) {
        const half8 bf0 = *(const half8*)&B_lds[0][0][lane][0];
        const half8 bf1 = *(const half8*)&B_lds[0][1][lane][0];
        const half8 bf2 = *(const half8*)&B_lds[0][2][lane][0];
        const half8 bf3 = *(const half8*)&B_lds[0][3][lane][0];
        f32x4 ao = {0.f,0.f,0.f,0.f};
        ao = MFMA(A[0][0], bf0, ao);
        ao = MFMA(A[0][1], bf1, ao);
        ao = MFMA(A[0][2], bf2, ao);
        ao = MFMA(A[0][3], bf3, ao);
        const float rv = __shfl_xor(ao[0], 8);
        if (lane < NB) out[(b0 + lane) * TLEN + (TLEN - 1)] = fmaf(SC_LO, rv, ao[0]);
    }
}

extern "C" void kernel_launch(void* const* d_in, const int* in_sizes, int n_in,
                              void* d_out, int out_size, void* d_ws, size_t ws_size,
                              hipStream_t stream) {
    const float* input = (const float*)d_in[0];
    const float* W_ih  = (const float*)d_in[1];
    const float* W_hh  = (const float*)d_in[2];
    const float* b_ih  = (const float*)d_in[3];
    const float* b_hh  = (const float*)d_in[4];
    const float* W_out = (const float*)d_in[5];
    const float* b_out = (const float*)d_in[6];
    float* out = (float*)d_out;

    const int B = in_sizes[0] / TLEN;  // 512
    lstm_mfma3<<<B / NB, BLOCK, 0, stream>>>(input, W_ih, W_hh, b_ih, b_hh,
                                             W_out, b_out, out);
}